// Round 20
// baseline (143.490 us; speedup 1.0000x reference)
//
#include <hip/hip_runtime.h>
#include <hip/hip_bf16.h>

#define VSZ 32000
#define DSZ 256
#define BSZ 32
#define MSZ 1024
#define PSZ 1025
#define VD  (VSZ * DSZ)
#define XBP 264     // xB row stride (bf16): 528B, 16B-aligned rows

// Workspace layout (float offsets)
#define OFF_U     32768                 // after int pos[M*B]
#define OFF_U0    40960
#define OFF_PP    49152                 // [P][B]
#define OFF_GIH   81952                 // [1536][B]
#define OFF_SC    131104                // [M][B] (idx = m*32+b)
#define OFF_PMAX  163872                // [B][128]
#define OFF_PSUM  167968                // [B][128]
#define OFF_PROJ  172064                // [V][B]
#define OFF_CNT   1196064               // persistent mod-12 counter (1 uint)

// Output layout (floats): prob_lg [B,M] | p_vocab [B,V] | hidden [1,B,D]
#define OUT_PV  (BSZ * MSZ)
#define OUT_HID (OUT_PV + BSZ * VSZ)

typedef __attribute__((ext_vector_type(8))) short bfrag;   // 8 bf16 (4 VGPR)
typedef __attribute__((ext_vector_type(4))) float f32x4;   // MFMA C/D

__device__ __forceinline__ short bfc(float f) {
    __hip_bfloat16 h = __float2bfloat16(f);   // RNE
    return __builtin_bit_cast(short, h);
}

__device__ __forceinline__ bfrag cvt8(float4 a, float4 b) {
    bfrag f;
    f[0] = bfc(a.x); f[1] = bfc(a.y); f[2] = bfc(a.z); f[3] = bfc(a.w);
    f[4] = bfc(b.x); f[5] = bfc(b.y); f[6] = bfc(b.z); f[7] = bfc(b.w);
    return f;
}

// ---------------------------------------------------------------------------
// stage x [32][256] f32 -> xB bf16 ([32][XBP])
__device__ __forceinline__ void stage_xb(const float* __restrict__ src,
                                         short* __restrict__ xB, int t) {
    for (int i = t; i < BSZ * 64; i += 256) {
        int b = i >> 6, c4 = i & 63;
        float4 v = ((const float4*)src)[i];
        short4 pk = make_short4(bfc(v.x), bfc(v.y), bfc(v.z), bfc(v.w));
        *(short4*)&xB[(size_t)b * XBP + c4 * 4] = pk;
    }
}

__device__ __forceinline__ void stage_xb_diff(const float* __restrict__ a,
                                              const float* __restrict__ c,
                                              short* __restrict__ xB, int t) {
    for (int i = t; i < BSZ * 64; i += 256) {
        int b = i >> 6, c4 = i & 63;
        float4 va = ((const float4*)a)[i];
        float4 vc = ((const float4*)c)[i];
        short4 pk = make_short4(bfc(va.x - vc.x), bfc(va.y - vc.y),
                                bfc(va.z - vc.z), bfc(va.w - vc.w));
        *(short4*)&xB[(size_t)b * XBP + c4 * 4] = pk;
    }
}

// ---------------------------------------------------------------------------
// Deep-pipelined direct MFMA pass (R17 structure).
template <int NRT>
__device__ __forceinline__ void mfma_deep(
    const float* __restrict__ W, int wstride, int rbeg, int nrows,
    const short* __restrict__ xB, f32x4 (&acc)[NRT][2], int t)
{
    const int lane = t & 63, w = t >> 6;
    const int m = lane & 15, kg = lane >> 4;
    bfrag xb[8][2];
#pragma unroll
    for (int kc = 0; kc < 8; ++kc) {
        xb[kc][0] = *(const bfrag*)&xB[(size_t)m * XBP + kc * 32 + kg * 8];
        xb[kc][1] = *(const bfrag*)&xB[(size_t)(16 + m) * XBP + kc * 32 + kg * 8];
    }
    const float* wp[NRT];
#pragma unroll
    for (int rt = 0; rt < NRT; ++rt) {
        int r = w * (NRT * 16) + rt * 16 + m;
        int rc = (r < nrows) ? r : 0;        // clamped rows discarded at store
        wp[rt] = W + (size_t)(rbeg + rc) * wstride + kg * 8;
    }
    float4 wbuf[4][NRT][2];
#pragma unroll
    for (int p = 0; p < 4; ++p)
#pragma unroll
        for (int rt = 0; rt < NRT; ++rt) {
            wbuf[p][rt][0] = *(const float4*)(wp[rt] + p * 32);
            wbuf[p][rt][1] = *(const float4*)(wp[rt] + p * 32 + 4);
        }
#pragma unroll
    for (int kt = 0; kt < 8; ++kt) {
        const int s = kt & 3;
#pragma unroll
        for (int rt = 0; rt < NRT; ++rt) {
            bfrag af = cvt8(wbuf[s][rt][0], wbuf[s][rt][1]);
            acc[rt][0] = __builtin_amdgcn_mfma_f32_16x16x32_bf16(af, xb[kt][0], acc[rt][0], 0, 0, 0);
            acc[rt][1] = __builtin_amdgcn_mfma_f32_16x16x32_bf16(af, xb[kt][1], acc[rt][1], 0, 0, 0);
        }
        if (kt < 4) {
#pragma unroll
            for (int rt = 0; rt < NRT; ++rt) {
                wbuf[s][rt][0] = *(const float4*)(wp[rt] + (kt + 4) * 32);
                wbuf[s][rt][1] = *(const float4*)(wp[rt] + (kt + 4) * 32 + 4);
            }
        }
    }
}

// C/D layout (HW-verified R15): col = lane&15 (b), row = (lane>>4)*4 + reg.
template <int NRT>
__device__ __forceinline__ void mfma_store(
    const f32x4 (&acc)[NRT][2], float* __restrict__ dest,
    const float* __restrict__ bias, size_t drow, size_t dcol,
    int rbeg, int nrows, int t)
{
    const int lane = t & 63, w = t >> 6;
    const int n = lane & 15, rq = lane >> 4;
#pragma unroll
    for (int rt = 0; rt < NRT; ++rt) {
#pragma unroll
        for (int g = 0; g < 4; ++g) {
            int r = w * (NRT * 16) + rt * 16 + rq * 4 + g;
            if (r < nrows) {
                float bv = bias ? bias[rbeg + r] : 0.f;
                dest[(size_t)(rbeg + r) * drow + (size_t)n * dcol] = acc[rt][0][g] + bv;
                dest[(size_t)(rbeg + r) * drow + (size_t)(16 + n) * dcol] = acc[rt][1][g] + bv;
            }
        }
    }
}

template <int NRT>
__device__ __forceinline__ void acc_zero(f32x4 (&acc)[NRT][2]) {
#pragma unroll
    for (int rt = 0; rt < NRT; ++rt)
#pragma unroll
        for (int bt = 0; bt < 2; ++bt) {
            f32x4 z = {0.f, 0.f, 0.f, 0.f};
            acc[rt][bt] = z;
        }
}

// ---------------------------------------------------------------------------
// K1: positions (blocks 0..31) || GRU matvec (blocks 32..43, 128 rows each).
// The LAST-finishing MV block (device mod-12 counter) also runs the GRU
// finalize inline — removes the separate k_grufin launch. Fences per G16.
__global__ __launch_bounds__(256, 1) void k_posgru(
    const int* __restrict__ story, const int* __restrict__ encq,
    const float* __restrict__ lasth, const float* __restrict__ C0,
    const float* __restrict__ gwih, const float* __restrict__ gwhh,
    const float* __restrict__ gbih, const float* __restrict__ gbhh,
    int* __restrict__ pos, float* __restrict__ gih,
    float* __restrict__ u, float* __restrict__ u0, float* __restrict__ hid,
    unsigned* __restrict__ cnt)
{
    __shared__ short xB[32 * XBP];
    __shared__ int wtot[4];
    __shared__ int lastS;
    int gid = blockIdx.x, t = threadIdx.x;
    int lane = t & 63, wid = t >> 6;
    if (gid < 32) {
        int b = gid, m0 = t * 4;
        int f0 = story[(size_t)((m0 + 0) * BSZ + b) * 4] != 0;
        int f1 = story[(size_t)((m0 + 1) * BSZ + b) * 4] != 0;
        int f2 = story[(size_t)((m0 + 2) * BSZ + b) * 4] != 0;
        int f3 = story[(size_t)((m0 + 3) * BSZ + b) * 4] != 0;
        int p1 = f0 + f1, p2 = p1 + f2, p3 = p2 + f3;
        int x = p3;
        for (int o = 1; o < 64; o <<= 1) {
            int v = __shfl_up(x, o, 64);
            if (lane >= o) x += v;
        }
        if (lane == 63) wtot[wid] = x;
        __syncthreads();
        int wo = 0;
        for (int i = 0; i < wid; ++i) wo += wtot[i];
        int base = wo + x - p3;
        pos[(m0 + 0) * BSZ + b] = f0 ? base + f0 : 0;
        pos[(m0 + 1) * BSZ + b] = f1 ? base + p1 : 0;
        pos[(m0 + 2) * BSZ + b] = f2 ? base + p2 : 0;
        pos[(m0 + 3) * BSZ + b] = f3 ? base + p3 : 0;
    } else {
        int k = gid - 32;               // 0..11
        bool isX = (k < 6);
        for (int i = t; i < BSZ * 64; i += 256) {
            int b = i >> 6, c4 = i & 63;
            float4 v = isX ? ((const float4*)(C0 + (size_t)encq[b] * DSZ))[c4]
                           : ((const float4*)(lasth + (size_t)b * DSZ))[c4];
            short4 pk = make_short4(bfc(v.x), bfc(v.y), bfc(v.z), bfc(v.w));
            *(short4*)&xB[(size_t)b * XBP + c4 * 4] = pk;
        }
        __syncthreads();
        int kr = isX ? k : k - 6;
        const float* W = isX ? gwih : gwhh;
        float* dest = gih + (isX ? 0 : 768 * BSZ);
        f32x4 acc[2][2];
        acc_zero<2>(acc);
        mfma_deep<2>(W, DSZ, kr * 128, 128, xB, acc, t);
        mfma_store<2>(acc, dest, nullptr, BSZ, 1, kr * 128, 128, t);
        // --- last-block GRU finalize (mod-12 counter: start-value agnostic) --
        __threadfence();                 // flush this block's gih to device scope
        __syncthreads();
        if (t == 0) {
            unsigned a = atomicAdd(cnt, 1u);
            lastS = ((a % 12u) == 11u) ? 1 : 0;
        }
        __syncthreads();
        if (lastS) {
            __threadfence();             // acquire: see all blocks' gih
            for (int idx = t; idx < BSZ * DSZ; idx += 256) {
                int b = idx & 31, d = idx >> 5;
                float gi0 = gih[(size_t)(0 * DSZ + d) * BSZ + b] + gbih[0 * DSZ + d];
                float gi1 = gih[(size_t)(1 * DSZ + d) * BSZ + b] + gbih[1 * DSZ + d];
                float gi2 = gih[(size_t)(2 * DSZ + d) * BSZ + b] + gbih[2 * DSZ + d];
                float gh0 = gih[(size_t)(3 * DSZ + d) * BSZ + b] + gbhh[0 * DSZ + d];
                float gh1 = gih[(size_t)(4 * DSZ + d) * BSZ + b] + gbhh[1 * DSZ + d];
                float gh2 = gih[(size_t)(5 * DSZ + d) * BSZ + b] + gbhh[2 * DSZ + d];
                float r = 1.f / (1.f + __expf(-(gi0 + gh0)));
                float z = 1.f / (1.f + __expf(-(gi1 + gh1)));
                float n = tanhf(gi2 + r * gh2);
                float h = lasth[(size_t)b * DSZ + d];
                float hn = (1.f - z) * n + z * h;
                int o = b * DSZ + d;
                u[o] = hn; u0[o] = hn; hid[o] = hn;
            }
        }
    }
}

// ---------------------------------------------------------------------------
// K3/K7: proj (blocks < nproj: 128 rows each) + posproj tail blocks.
// proj/pp stored [V][B] (coalesced MFMA stores).
__global__ __launch_bounds__(256, 1) void k_proj(
    const float* __restrict__ Ct, const float* __restrict__ postab,
    const float* __restrict__ u, float* __restrict__ proj,
    float* __restrict__ pp, int nproj)
{
    __shared__ short xB[32 * XBP];
    int gid = blockIdx.x, t = threadIdx.x;
    stage_xb(u, xB, t);
    __syncthreads();
    f32x4 acc[2][2];
    acc_zero<2>(acc);
    if (gid < nproj) {
        int rb = gid * 128;
        mfma_deep<2>(Ct, DSZ, rb, 128, xB, acc, t);
        mfma_store<2>(acc, proj, nullptr, BSZ, 1, rb, 128, t);
    } else {
        int rb = (gid - nproj) * 128;
        int nr = min(128, PSZ - rb);
        mfma_deep<2>(postab, DSZ, rb, nr, xB, acc, t);
        mfma_store<2>(acc, pp, nullptr, BSZ, 1, rb, nr, t);
    }
}

// ---------------------------------------------------------------------------
// K4: scores (+ per-block softmax stats for hop<2, b-major layout).
__global__ void k_scores(const int* __restrict__ story, const int* __restrict__ pos,
                         const float* __restrict__ proj, const float* __restrict__ pp,
                         float* __restrict__ sc, float* __restrict__ pmax,
                         float* __restrict__ psum, float* __restrict__ outlg, int hop)
{
    __shared__ float red[256];
    int gid = blockIdx.x, t = threadIdx.x;
    int idx = gid * 256 + t;
    int b = idx & 31, m = idx >> 5;
    int4 st = *(const int4*)&story[(size_t)idx * 4];
    float s = proj[(size_t)st.x * BSZ + b] + proj[(size_t)st.y * BSZ + b] +
              proj[(size_t)st.z * BSZ + b] + proj[(size_t)st.w * BSZ + b];
    if (hop == 0) s += pp[(size_t)pos[idx] * BSZ + b];
    if (hop == 2) { outlg[b * MSZ + m] = s; return; }
    sc[idx] = s;
    red[t] = s;
    __syncthreads();
    if (t < 32) {
        float mx = red[t];
#pragma unroll
        for (int k = 1; k < 8; ++k) mx = fmaxf(mx, red[k * 32 + t]);
        float sm = 0.f;
#pragma unroll
        for (int k = 0; k < 8; ++k) sm += __expf(red[k * 32 + t] - mx);
        pmax[(size_t)t * 128 + gid] = mx;      // [b][chunk]
        psum[(size_t)t * 128 + gid] = sm;
    }
}

// ---------------------------------------------------------------------------
// K5: gather-PV. 1024 blocks = (32 mc x 32 b), 256 thr = 4 m-groups x 64 d-lanes.
// Stat combine: single wave, shuffle reduce over b-major stats (2 lines).
__global__ __launch_bounds__(256) void k_okpv(
    const int* __restrict__ story, const float* __restrict__ sc,
    const float* __restrict__ pmax, const float* __restrict__ psum,
    const float* __restrict__ Ct, float* __restrict__ u)
{
    int b = blockIdx.x & 31, mc = blockIdx.x >> 5;
    int t = threadIdx.x;
    __shared__ float msS[2];
    __shared__ float pl[32];
    __shared__ float4 pt[4][64];
    if (t < 64) {
        float m1 = pmax[(size_t)b * 128 + t];
        float m2 = pmax[(size_t)b * 128 + 64 + t];
        float s1 = psum[(size_t)b * 128 + t];
        float s2 = psum[(size_t)b * 128 + 64 + t];
        float mx = fmaxf(m1, m2);
#pragma unroll
        for (int o = 32; o > 0; o >>= 1) mx = fmaxf(mx, __shfl_xor(mx, o, 64));
        float ss = s1 * __expf(m1 - mx) + s2 * __expf(m2 - mx);
#pragma unroll
        for (int o = 32; o > 0; o >>= 1) ss += __shfl_xor(ss, o, 64);
        if (t == 0) { msS[0] = mx; msS[1] = ss; }
    }
    __syncthreads();
    float M = msS[0], S = msS[1];
    if (t < 32) pl[t] = __expf(sc[(size_t)(mc * 32 + t) * BSZ + b] - M) / S;
    __syncthreads();
    int dl = t & 63, mg = t >> 6;
    int mbase = mc * 32 + mg * 8;
    int4 sts[8]; float pws[8];
#pragma unroll
    for (int i = 0; i < 8; ++i) {
        sts[i] = *(const int4*)&story[(size_t)((mbase + i) * BSZ + b) * 4];
        pws[i] = pl[mg * 8 + i];
    }
    float4 acc = make_float4(0.f, 0.f, 0.f, 0.f);
    float4 bufA[4], bufB[4];
#define LOADR(dst, s_)                                                \
    dst[0] = ((const float4*)(Ct + (size_t)(s_).x * DSZ))[dl];        \
    dst[1] = ((const float4*)(Ct + (size_t)(s_).y * DSZ))[dl];        \
    dst[2] = ((const float4*)(Ct + (size_t)(s_).z * DSZ))[dl];        \
    dst[3] = ((const float4*)(Ct + (size_t)(s_).w * DSZ))[dl];
#define STEP(i, CUR)                                                  \
    {                                                                 \
        float p_ = pws[i];                                            \
        float4 a0 = CUR[0], a1 = CUR[1], a2 = CUR[2], a3 = CUR[3];    \
        if ((i) + 2 < 8) { LOADR(CUR, sts[(i) + 2]); }                \
        acc.x += p_ * (a0.x + a1.x + a2.x + a3.x);                    \
        acc.y += p_ * (a0.y + a1.y + a2.y + a3.y);                    \
        acc.z += p_ * (a0.z + a1.z + a2.z + a3.z);                    \
        acc.w += p_ * (a0.w + a1.w + a2.w + a3.w);                    \
    }
    LOADR(bufA, sts[0]);
    LOADR(bufB, sts[1]);
    STEP(0, bufA) STEP(1, bufB) STEP(2, bufA) STEP(3, bufB)
    STEP(4, bufA) STEP(5, bufB) STEP(6, bufA) STEP(7, bufB)
#undef STEP
#undef LOADR
    pt[mg][dl] = acc;
    __syncthreads();
    if (t < 64) {
        float4 s0 = pt[0][t], s1 = pt[1][t], s2 = pt[2][t], s3 = pt[3][t];
        float* dst = &u[(size_t)b * DSZ + t * 4];
        atomicAdd(dst + 0, s0.x + s1.x + s2.x + s3.x);
        atomicAdd(dst + 1, s0.y + s1.y + s2.y + s3.y);
        atomicAdd(dst + 2, s0.z + s1.z + s2.z + s3.z);
        atomicAdd(dst + 3, s0.w + s1.w + s2.w + s3.w);
    }
}

// ---------------------------------------------------------------------------
// K6: tail0 — balanced 750 blocks: pvocab (0..499, 64 rows, 2 K-passes) ||
// proj h1 (500..749, 128 rows). All blocks read ~128 KB.
__global__ __launch_bounds__(256, 1) void k_tail0(
    const float* __restrict__ C1, const float* __restrict__ u,
    const float* __restrict__ u0, const float* __restrict__ W1w,
    const float* __restrict__ W1b, float* __restrict__ proj,
    float* __restrict__ out_pv)
{
    __shared__ short xB[32 * XBP];
    int gid = blockIdx.x, t = threadIdx.x;
    if (gid < 500) {
        int rb = gid * 64;
        f32x4 acc[1][2];
        acc_zero<1>(acc);
        stage_xb(u0, xB, t);                 // pass 1: u0 vs W1w cols 0..255
        __syncthreads();
        mfma_deep<1>(W1w, 512, rb, 64, xB, acc, t);
        __syncthreads();
        stage_xb_diff(u, u0, xB, t);         // pass 2: o_k vs cols 256..511
        __syncthreads();
        mfma_deep<1>(W1w + 256, 512, rb, 64, xB, acc, t);
        mfma_store<1>(acc, out_pv, W1b, 1, VSZ, rb, 64, t);
    } else {
        f32x4 acc[2][2];
        acc_zero<2>(acc);
        stage_xb(u, xB, t);
        __syncthreads();
        int rb = (gid - 500) * 128;
        mfma_deep<2>(C1, DSZ, rb, 128, xB, acc, t);
        mfma_store<2>(acc, proj, nullptr, BSZ, 1, rb, 128, t);
    }
}

// ---------------------------------------------------------------------------
extern "C" void kernel_launch(void* const* d_in, const int* in_sizes, int n_in,
                              void* d_out, int out_size, void* d_ws, size_t ws_size,
                              hipStream_t stream) {
    const int*   story  = (const int*)d_in[0];
    const int*   encq   = (const int*)d_in[1];
    const float* lasth  = (const float*)d_in[2];
    const float* C      = (const float*)d_in[3];
    const float* postab = (const float*)d_in[4];
    const float* W1w    = (const float*)d_in[5];
    const float* W1b    = (const float*)d_in[6];
    const float* gwih   = (const float*)d_in[7];
    const float* gwhh   = (const float*)d_in[8];
    const float* gbih   = (const float*)d_in[9];
    const float* gbhh   = (const float*)d_in[10];

    float* out = (float*)d_out;
    float* wsf = (float*)d_ws;
    int*   pos  = (int*)d_ws;
    float* u    = wsf + OFF_U;
    float* u0   = wsf + OFF_U0;
    float* pp   = wsf + OFF_PP;
    float* gih  = wsf + OFF_GIH;
    float* sc   = wsf + OFF_SC;
    float* pmax = wsf + OFF_PMAX;
    float* psum = wsf + OFF_PSUM;
    float* proj = wsf + OFF_PROJ;
    unsigned* cnt = (unsigned*)(wsf + OFF_CNT);

    k_posgru<<<44, 256, 0, stream>>>(story, encq, lasth, C, gwih, gwhh,
                                     gbih, gbhh, pos, gih, u, u0,
                                     out + OUT_HID, cnt);
    // proj hop0 (250 blocks x 128 rows) + posproj (9 blocks)
    k_proj<<<259, 256, 0, stream>>>(C, postab, u, proj, pp, 250);

    for (int hop = 0; hop < 3; ++hop) {
        k_scores<<<128, 256, 0, stream>>>(story, pos, proj, pp, sc, pmax, psum,
                                          out, hop);
        if (hop == 2) break;
        k_okpv<<<1024, 256, 0, stream>>>(story, sc, pmax, psum,
                                         C + (size_t)(hop + 1) * VD, u);
        if (hop == 0) {
            k_tail0<<<750, 256, 0, stream>>>(C + (size_t)VD, u, u0, W1w, W1b,
                                             proj, out + OUT_PV);
        } else {
            k_proj<<<250, 256, 0, stream>>>(C + (size_t)2 * VD, nullptr, u, proj,
                                            nullptr, 250);
        }
    }
}

// Round 21
// 116.475 us; speedup vs baseline: 1.2319x; 1.2319x over previous
//
#include <hip/hip_runtime.h>
#include <hip/hip_bf16.h>

#define VSZ 32000
#define DSZ 256
#define BSZ 32
#define MSZ 1024
#define PSZ 1025
#define VD  (VSZ * DSZ)
#define XBP 264     // xB row stride (bf16): 528B, 16B-aligned rows

// Workspace layout (float offsets)
#define OFF_U     32768                 // after int pos[M*B]
#define OFF_U0    40960
#define OFF_PP    49152                 // [P][B]
#define OFF_GIH   81952                 // [1536][B]
#define OFF_SC    131104                // [M][B] (idx = m*32+b)
#define OFF_PMAX  163872                // [B][128]
#define OFF_PSUM  167968                // [B][128]
#define OFF_PROJ  172064                // [V][B]

// Output layout (floats): prob_lg [B,M] | p_vocab [B,V] | hidden [1,B,D]
#define OUT_PV  (BSZ * MSZ)
#define OUT_HID (OUT_PV + BSZ * VSZ)

typedef __attribute__((ext_vector_type(8))) short bfrag;   // 8 bf16 (4 VGPR)
typedef __attribute__((ext_vector_type(4))) float f32x4;   // MFMA C/D

__device__ __forceinline__ short bfc(float f) {
    __hip_bfloat16 h = __float2bfloat16(f);   // RNE
    return __builtin_bit_cast(short, h);
}

__device__ __forceinline__ bfrag cvt8(float4 a, float4 b) {
    bfrag f;
    f[0] = bfc(a.x); f[1] = bfc(a.y); f[2] = bfc(a.z); f[3] = bfc(a.w);
    f[4] = bfc(b.x); f[5] = bfc(b.y); f[6] = bfc(b.z); f[7] = bfc(b.w);
    return f;
}

// ---------------------------------------------------------------------------
// stage x [32][256] f32 -> xB bf16 ([32][XBP])
__device__ __forceinline__ void stage_xb(const float* __restrict__ src,
                                         short* __restrict__ xB, int t) {
    for (int i = t; i < BSZ * 64; i += 256) {
        int b = i >> 6, c4 = i & 63;
        float4 v = ((const float4*)src)[i];
        short4 pk = make_short4(bfc(v.x), bfc(v.y), bfc(v.z), bfc(v.w));
        *(short4*)&xB[(size_t)b * XBP + c4 * 4] = pk;
    }
}

__device__ __forceinline__ void stage_xb_diff(const float* __restrict__ a,
                                              const float* __restrict__ c,
                                              short* __restrict__ xB, int t) {
    for (int i = t; i < BSZ * 64; i += 256) {
        int b = i >> 6, c4 = i & 63;
        float4 va = ((const float4*)a)[i];
        float4 vc = ((const float4*)c)[i];
        short4 pk = make_short4(bfc(va.x - vc.x), bfc(va.y - vc.y),
                                bfc(va.z - vc.z), bfc(va.w - vc.w));
        *(short4*)&xB[(size_t)b * XBP + c4 * 4] = pk;
    }
}

// ---------------------------------------------------------------------------
// Deep-pipelined direct MFMA pass (R17 structure).
template <int NRT>
__device__ __forceinline__ void mfma_deep(
    const float* __restrict__ W, int wstride, int rbeg, int nrows,
    const short* __restrict__ xB, f32x4 (&acc)[NRT][2], int t)
{
    const int lane = t & 63, w = t >> 6;
    const int m = lane & 15, kg = lane >> 4;
    bfrag xb[8][2];
#pragma unroll
    for (int kc = 0; kc < 8; ++kc) {
        xb[kc][0] = *(const bfrag*)&xB[(size_t)m * XBP + kc * 32 + kg * 8];
        xb[kc][1] = *(const bfrag*)&xB[(size_t)(16 + m) * XBP + kc * 32 + kg * 8];
    }
    const float* wp[NRT];
#pragma unroll
    for (int rt = 0; rt < NRT; ++rt) {
        int r = w * (NRT * 16) + rt * 16 + m;
        int rc = (r < nrows) ? r : 0;        // clamped rows discarded at store
        wp[rt] = W + (size_t)(rbeg + rc) * wstride + kg * 8;
    }
    float4 wbuf[4][NRT][2];
#pragma unroll
    for (int p = 0; p < 4; ++p)
#pragma unroll
        for (int rt = 0; rt < NRT; ++rt) {
            wbuf[p][rt][0] = *(const float4*)(wp[rt] + p * 32);
            wbuf[p][rt][1] = *(const float4*)(wp[rt] + p * 32 + 4);
        }
#pragma unroll
    for (int kt = 0; kt < 8; ++kt) {
        const int s = kt & 3;
#pragma unroll
        for (int rt = 0; rt < NRT; ++rt) {
            bfrag af = cvt8(wbuf[s][rt][0], wbuf[s][rt][1]);
            acc[rt][0] = __builtin_amdgcn_mfma_f32_16x16x32_bf16(af, xb[kt][0], acc[rt][0], 0, 0, 0);
            acc[rt][1] = __builtin_amdgcn_mfma_f32_16x16x32_bf16(af, xb[kt][1], acc[rt][1], 0, 0, 0);
        }
        if (kt < 4) {
#pragma unroll
            for (int rt = 0; rt < NRT; ++rt) {
                wbuf[s][rt][0] = *(const float4*)(wp[rt] + (kt + 4) * 32);
                wbuf[s][rt][1] = *(const float4*)(wp[rt] + (kt + 4) * 32 + 4);
            }
        }
    }
}

// C/D layout (HW-verified R15): col = lane&15 (b), row = (lane>>4)*4 + reg.
template <int NRT>
__device__ __forceinline__ void mfma_store(
    const f32x4 (&acc)[NRT][2], float* __restrict__ dest,
    const float* __restrict__ bias, size_t drow, size_t dcol,
    int rbeg, int nrows, int t)
{
    const int lane = t & 63, w = t >> 6;
    const int n = lane & 15, rq = lane >> 4;
#pragma unroll
    for (int rt = 0; rt < NRT; ++rt) {
#pragma unroll
        for (int g = 0; g < 4; ++g) {
            int r = w * (NRT * 16) + rt * 16 + rq * 4 + g;
            if (r < nrows) {
                float bv = bias ? bias[rbeg + r] : 0.f;
                dest[(size_t)(rbeg + r) * drow + (size_t)n * dcol] = acc[rt][0][g] + bv;
                dest[(size_t)(rbeg + r) * drow + (size_t)(16 + n) * dcol] = acc[rt][1][g] + bv;
            }
        }
    }
}

template <int NRT>
__device__ __forceinline__ void acc_zero(f32x4 (&acc)[NRT][2]) {
#pragma unroll
    for (int rt = 0; rt < NRT; ++rt)
#pragma unroll
        for (int bt = 0; bt < 2; ++bt) {
            f32x4 z = {0.f, 0.f, 0.f, 0.f};
            acc[rt][bt] = z;
        }
}

// ---------------------------------------------------------------------------
// K1: positions (blocks 0..31) || GRU matvec (blocks 32..43, 128 rows each)
__global__ __launch_bounds__(256, 1) void k_posgru(
    const int* __restrict__ story, const int* __restrict__ encq,
    const float* __restrict__ lasth, const float* __restrict__ C0,
    const float* __restrict__ gwih, const float* __restrict__ gwhh,
    int* __restrict__ pos, float* __restrict__ gih)
{
    __shared__ short xB[32 * XBP];
    __shared__ int wtot[4];
    int gid = blockIdx.x, t = threadIdx.x;
    int lane = t & 63, wid = t >> 6;
    if (gid < 32) {
        int b = gid, m0 = t * 4;
        int f0 = story[(size_t)((m0 + 0) * BSZ + b) * 4] != 0;
        int f1 = story[(size_t)((m0 + 1) * BSZ + b) * 4] != 0;
        int f2 = story[(size_t)((m0 + 2) * BSZ + b) * 4] != 0;
        int f3 = story[(size_t)((m0 + 3) * BSZ + b) * 4] != 0;
        int p1 = f0 + f1, p2 = p1 + f2, p3 = p2 + f3;
        int x = p3;
        for (int o = 1; o < 64; o <<= 1) {
            int v = __shfl_up(x, o, 64);
            if (lane >= o) x += v;
        }
        if (lane == 63) wtot[wid] = x;
        __syncthreads();
        int wo = 0;
        for (int i = 0; i < wid; ++i) wo += wtot[i];
        int base = wo + x - p3;
        pos[(m0 + 0) * BSZ + b] = f0 ? base + f0 : 0;
        pos[(m0 + 1) * BSZ + b] = f1 ? base + p1 : 0;
        pos[(m0 + 2) * BSZ + b] = f2 ? base + p2 : 0;
        pos[(m0 + 3) * BSZ + b] = f3 ? base + p3 : 0;
    } else {
        int k = gid - 32;               // 0..11
        bool isX = (k < 6);
        for (int i = t; i < BSZ * 64; i += 256) {
            int b = i >> 6, c4 = i & 63;
            float4 v = isX ? ((const float4*)(C0 + (size_t)encq[b] * DSZ))[c4]
                           : ((const float4*)(lasth + (size_t)b * DSZ))[c4];
            short4 pk = make_short4(bfc(v.x), bfc(v.y), bfc(v.z), bfc(v.w));
            *(short4*)&xB[(size_t)b * XBP + c4 * 4] = pk;
        }
        __syncthreads();
        int kr = isX ? k : k - 6;
        const float* W = isX ? gwih : gwhh;
        float* dest = gih + (isX ? 0 : 768 * BSZ);
        f32x4 acc[2][2];
        acc_zero<2>(acc);
        mfma_deep<2>(W, DSZ, kr * 128, 128, xB, acc, t);
        mfma_store<2>(acc, dest, nullptr, BSZ, 1, kr * 128, 128, t);
    }
}

// ---------------------------------------------------------------------------
// K2: GRU finalize. 32 x 256, idx = b + 32*d (coalesced gih reads).
__global__ void k_grufin(const float* __restrict__ gih,
                         const float* __restrict__ gbih, const float* __restrict__ gbhh,
                         const float* __restrict__ lasth,
                         float* __restrict__ u, float* __restrict__ u0,
                         float* __restrict__ hid)
{
    int idx = blockIdx.x * 256 + threadIdx.x;
    int b = idx & 31, d = idx >> 5;
    float gi0 = gih[(size_t)(0 * DSZ + d) * BSZ + b] + gbih[0 * DSZ + d];
    float gi1 = gih[(size_t)(1 * DSZ + d) * BSZ + b] + gbih[1 * DSZ + d];
    float gi2 = gih[(size_t)(2 * DSZ + d) * BSZ + b] + gbih[2 * DSZ + d];
    float gh0 = gih[(size_t)(3 * DSZ + d) * BSZ + b] + gbhh[0 * DSZ + d];
    float gh1 = gih[(size_t)(4 * DSZ + d) * BSZ + b] + gbhh[1 * DSZ + d];
    float gh2 = gih[(size_t)(5 * DSZ + d) * BSZ + b] + gbhh[2 * DSZ + d];
    float r = 1.f / (1.f + __expf(-(gi0 + gh0)));
    float z = 1.f / (1.f + __expf(-(gi1 + gh1)));
    float n = tanhf(gi2 + r * gh2);
    float h = lasth[(size_t)b * DSZ + d];
    float hn = (1.f - z) * n + z * h;
    int o = b * DSZ + d;
    u[o] = hn; u0[o] = hn; hid[o] = hn;
}

// ---------------------------------------------------------------------------
// K3/K7: proj (blocks < nproj: 128 rows each) + posproj tail blocks.
// proj/pp stored [V][B] (coalesced MFMA stores).
__global__ __launch_bounds__(256, 1) void k_proj(
    const float* __restrict__ Ct, const float* __restrict__ postab,
    const float* __restrict__ u, float* __restrict__ proj,
    float* __restrict__ pp, int nproj)
{
    __shared__ short xB[32 * XBP];
    int gid = blockIdx.x, t = threadIdx.x;
    stage_xb(u, xB, t);
    __syncthreads();
    f32x4 acc[2][2];
    acc_zero<2>(acc);
    if (gid < nproj) {
        int rb = gid * 128;
        mfma_deep<2>(Ct, DSZ, rb, 128, xB, acc, t);
        mfma_store<2>(acc, proj, nullptr, BSZ, 1, rb, 128, t);
    } else {
        int rb = (gid - nproj) * 128;
        int nr = min(128, PSZ - rb);
        mfma_deep<2>(postab, DSZ, rb, nr, xB, acc, t);
        mfma_store<2>(acc, pp, nullptr, BSZ, 1, rb, nr, t);
    }
}

// ---------------------------------------------------------------------------
// K4: scores (+ per-block softmax stats for hop<2, b-major layout).
__global__ void k_scores(const int* __restrict__ story, const int* __restrict__ pos,
                         const float* __restrict__ proj, const float* __restrict__ pp,
                         float* __restrict__ sc, float* __restrict__ pmax,
                         float* __restrict__ psum, float* __restrict__ outlg, int hop)
{
    __shared__ float red[256];
    int gid = blockIdx.x, t = threadIdx.x;
    int idx = gid * 256 + t;
    int b = idx & 31, m = idx >> 5;
    int4 st = *(const int4*)&story[(size_t)idx * 4];
    float s = proj[(size_t)st.x * BSZ + b] + proj[(size_t)st.y * BSZ + b] +
              proj[(size_t)st.z * BSZ + b] + proj[(size_t)st.w * BSZ + b];
    if (hop == 0) s += pp[(size_t)pos[idx] * BSZ + b];
    if (hop == 2) { outlg[b * MSZ + m] = s; return; }
    sc[idx] = s;
    red[t] = s;
    __syncthreads();
    if (t < 32) {
        float mx = red[t];
#pragma unroll
        for (int k = 1; k < 8; ++k) mx = fmaxf(mx, red[k * 32 + t]);
        float sm = 0.f;
#pragma unroll
        for (int k = 0; k < 8; ++k) sm += __expf(red[k * 32 + t] - mx);
        pmax[(size_t)t * 128 + gid] = mx;      // [b][chunk]
        psum[(size_t)t * 128 + gid] = sm;
    }
}

// ---------------------------------------------------------------------------
// K5: gather-PV. 1024 blocks = (32 mc x 32 b), 256 thr = 4 m-groups x 64 d-lanes.
// Stat combine: single wave, shuffle reduce over b-major stats (2 lines).
__global__ __launch_bounds__(256) void k_okpv(
    const int* __restrict__ story, const float* __restrict__ sc,
    const float* __restrict__ pmax, const float* __restrict__ psum,
    const float* __restrict__ Ct, float* __restrict__ u)
{
    int b = blockIdx.x & 31, mc = blockIdx.x >> 5;
    int t = threadIdx.x;
    __shared__ float msS[2];
    __shared__ float pl[32];
    __shared__ float4 pt[4][64];
    if (t < 64) {
        float m1 = pmax[(size_t)b * 128 + t];
        float m2 = pmax[(size_t)b * 128 + 64 + t];
        float s1 = psum[(size_t)b * 128 + t];
        float s2 = psum[(size_t)b * 128 + 64 + t];
        float mx = fmaxf(m1, m2);
#pragma unroll
        for (int o = 32; o > 0; o >>= 1) mx = fmaxf(mx, __shfl_xor(mx, o, 64));
        float ss = s1 * __expf(m1 - mx) + s2 * __expf(m2 - mx);
#pragma unroll
        for (int o = 32; o > 0; o >>= 1) ss += __shfl_xor(ss, o, 64);
        if (t == 0) { msS[0] = mx; msS[1] = ss; }
    }
    __syncthreads();
    float M = msS[0], S = msS[1];
    if (t < 32) pl[t] = __expf(sc[(size_t)(mc * 32 + t) * BSZ + b] - M) / S;
    __syncthreads();
    int dl = t & 63, mg = t >> 6;
    int mbase = mc * 32 + mg * 8;
    int4 sts[8]; float pws[8];
#pragma unroll
    for (int i = 0; i < 8; ++i) {
        sts[i] = *(const int4*)&story[(size_t)((mbase + i) * BSZ + b) * 4];
        pws[i] = pl[mg * 8 + i];
    }
    float4 acc = make_float4(0.f, 0.f, 0.f, 0.f);
    float4 bufA[4], bufB[4];
#define LOADR(dst, s_)                                                \
    dst[0] = ((const float4*)(Ct + (size_t)(s_).x * DSZ))[dl];        \
    dst[1] = ((const float4*)(Ct + (size_t)(s_).y * DSZ))[dl];        \
    dst[2] = ((const float4*)(Ct + (size_t)(s_).z * DSZ))[dl];        \
    dst[3] = ((const float4*)(Ct + (size_t)(s_).w * DSZ))[dl];
#define STEP(i, CUR)                                                  \
    {                                                                 \
        float p_ = pws[i];                                            \
        float4 a0 = CUR[0], a1 = CUR[1], a2 = CUR[2], a3 = CUR[3];    \
        if ((i) + 2 < 8) { LOADR(CUR, sts[(i) + 2]); }                \
        acc.x += p_ * (a0.x + a1.x + a2.x + a3.x);                    \
        acc.y += p_ * (a0.y + a1.y + a2.y + a3.y);                    \
        acc.z += p_ * (a0.z + a1.z + a2.z + a3.z);                    \
        acc.w += p_ * (a0.w + a1.w + a2.w + a3.w);                    \
    }
    LOADR(bufA, sts[0]);
    LOADR(bufB, sts[1]);
    STEP(0, bufA) STEP(1, bufB) STEP(2, bufA) STEP(3, bufB)
    STEP(4, bufA) STEP(5, bufB) STEP(6, bufA) STEP(7, bufB)
#undef STEP
#undef LOADR
    pt[mg][dl] = acc;
    __syncthreads();
    if (t < 64) {
        float4 s0 = pt[0][t], s1 = pt[1][t], s2 = pt[2][t], s3 = pt[3][t];
        float* dst = &u[(size_t)b * DSZ + t * 4];
        atomicAdd(dst + 0, s0.x + s1.x + s2.x + s3.x);
        atomicAdd(dst + 1, s0.y + s1.y + s2.y + s3.y);
        atomicAdd(dst + 2, s0.z + s1.z + s2.z + s3.z);
        atomicAdd(dst + 3, s0.w + s1.w + s2.w + s3.w);
    }
}

// ---------------------------------------------------------------------------
// K6: tail0 — balanced 750 blocks: pvocab (0..499, 64 rows, 2 K-passes) ||
// proj h1 (500..749, 128 rows). All blocks read ~128 KB.
__global__ __launch_bounds__(256, 1) void k_tail0(
    const float* __restrict__ C1, const float* __restrict__ u,
    const float* __restrict__ u0, const float* __restrict__ W1w,
    const float* __restrict__ W1b, float* __restrict__ proj,
    float* __restrict__ out_pv)
{
    __shared__ short xB[32 * XBP];
    int gid = blockIdx.x, t = threadIdx.x;
    if (gid < 500) {
        int rb = gid * 64;
        f32x4 acc[1][2];
        acc_zero<1>(acc);
        stage_xb(u0, xB, t);                 // pass 1: u0 vs W1w cols 0..255
        __syncthreads();
        mfma_deep<1>(W1w, 512, rb, 64, xB, acc, t);
        __syncthreads();
        stage_xb_diff(u, u0, xB, t);         // pass 2: o_k vs cols 256..511
        __syncthreads();
        mfma_deep<1>(W1w + 256, 512, rb, 64, xB, acc, t);
        mfma_store<1>(acc, out_pv, W1b, 1, VSZ, rb, 64, t);
    } else {
        f32x4 acc[2][2];
        acc_zero<2>(acc);
        stage_xb(u, xB, t);
        __syncthreads();
        int rb = (gid - 500) * 128;
        mfma_deep<2>(C1, DSZ, rb, 128, xB, acc, t);
        mfma_store<2>(acc, proj, nullptr, BSZ, 1, rb, 128, t);
    }
}

// ---------------------------------------------------------------------------
extern "C" void kernel_launch(void* const* d_in, const int* in_sizes, int n_in,
                              void* d_out, int out_size, void* d_ws, size_t ws_size,
                              hipStream_t stream) {
    const int*   story  = (const int*)d_in[0];
    const int*   encq   = (const int*)d_in[1];
    const float* lasth  = (const float*)d_in[2];
    const float* C      = (const float*)d_in[3];
    const float* postab = (const float*)d_in[4];
    const float* W1w    = (const float*)d_in[5];
    const float* W1b    = (const float*)d_in[6];
    const float* gwih   = (const float*)d_in[7];
    const float* gwhh   = (const float*)d_in[8];
    const float* gbih   = (const float*)d_in[9];
    const float* gbhh   = (const float*)d_in[10];

    float* out = (float*)d_out;
    float* wsf = (float*)d_ws;
    int*   pos  = (int*)d_ws;
    float* u    = wsf + OFF_U;
    float* u0   = wsf + OFF_U0;
    float* pp   = wsf + OFF_PP;
    float* gih  = wsf + OFF_GIH;
    float* sc   = wsf + OFF_SC;
    float* pmax = wsf + OFF_PMAX;
    float* psum = wsf + OFF_PSUM;
    float* proj = wsf + OFF_PROJ;

    k_posgru<<<44, 256, 0, stream>>>(story, encq, lasth, C, gwih, gwhh, pos, gih);
    k_grufin<<<32, 256, 0, stream>>>(gih, gbih, gbhh, lasth, u, u0, out + OUT_HID);
    // proj hop0 (250 blocks x 128 rows) + posproj (9 blocks)
    k_proj<<<259, 256, 0, stream>>>(C, postab, u, proj, pp, 250);

    for (int hop = 0; hop < 3; ++hop) {
        k_scores<<<128, 256, 0, stream>>>(story, pos, proj, pp, sc, pmax, psum,
                                          out, hop);
        if (hop == 2) break;
        k_okpv<<<1024, 256, 0, stream>>>(story, sc, pmax, psum,
                                         C + (size_t)(hop + 1) * VD, u);
        if (hop == 0) {
            k_tail0<<<750, 256, 0, stream>>>(C + (size_t)VD, u, u0, W1w, W1b,
                                             proj, out + OUT_PV);
        } else {
            k_proj<<<250, 256, 0, stream>>>(C + (size_t)2 * VD, nullptr, u, proj,
                                            nullptr, 250);
        }
    }
}